// Round 13
// baseline (494.468 us; speedup 1.0000x reference)
//
#include <hip/hip_runtime.h>
#include <hip/hip_bf16.h>

// CentroidsFlowAD: out[row] = sqrt(max(||e||^2 + min_col(||c||^2 - 2 e.c), 0))
// rows = 32*3136 = 100352, cols = 2048 centroids, K = 1024.
//
// Fast path (needs ~112 MiB ws), fp8 e4m3 cross-term (row norms exact fp32):
//   1. rowsq_fp8pack on centroids -> c8 (packed fp8, seg-128 layout) + csq
//   2. rowsq_fp8pack on embeds    -> e8 + esq
//   3. gemm_min_mx: 128x128 tile, BK=128, 4 waves (64x64), MX-scaled
//      mfma_scale 16x16x128 (unit e8m0; layout verified R9-R12).
//      R13: B fragments load DIRECTLY from global (c8 is 2 MB, L2-resident
//      per XCD) -- the B LDS round-trip (stage 16K + read 32K per block-
//      tile, half of all LDS traffic) bought nothing L2 doesn't provide.
//      LDS now holds A only (16 KB, single buffer), 3 blocks/CU at
//      launch_bounds(256,3) (R11: the no-spill occupancy sweet spot;
//      R12 showed dbuf@2blk loses to TLP@3blk).
//      Schedule: WAITVM(8) retires the 4 A-stage loads (oldest; FENCE
//      pins A-before-B issue order), B(kt)'s 8 loads stay in flight
//      across B1 (compiler inserts precise vmcnt before MFMA use) ->
//      B1 -> compute -> LGKM0 -> B2 -> stageA(kt+1) -> loadB(kt+1).
//   4. final_min: 16-way min + sqrt
// fp8 K-packed row layout (128B per K-seg of 128): 16B slot s=ksp*4+g holds
// k = {32*(2ksp)+8g..+7 | 32*(2ksp+1)+8g..+7}. LDS slot s == global bytes
// kt*128+s*16 (write/read swizzles cancel), so B frag lo/hi = global
// colB[n] + kt*128 and +64 -- all 13-bit immediates when unrolled.
// A slot swizzle s^(row&7) (full 8-spread; proven R5-R12).
// Fallback: round-1 fused kernel (proven, bf16).

typedef __bf16 bf16x8 __attribute__((ext_vector_type(8)));
typedef __bf16 bf16x4 __attribute__((ext_vector_type(4)));
typedef float f32x4 __attribute__((ext_vector_type(4)));
typedef int i32x4 __attribute__((ext_vector_type(4)));
typedef int i32x8 __attribute__((ext_vector_type(8)));

#define N_ROWS 100352
#define M_CENT 2048
#define D_K 1024

// fp8 fast-path geometry
#define BM4 128
#define BN4 128
#define BK4 128
#define NT4 (D_K / BK4)                // 8 K-tiles
#define NCT4 (M_CENT / BN4)            // 16 col tiles
#define NBLK4 ((N_ROWS / BM4) * NCT4)  // 12544
#define BPX4 (NBLK4 / 8)               // 1568 per XCD

// fallback geometry (round-1, unchanged)
#define TM 128
#define TN 128
#define BK 64
#define NT_TILES (M_CENT / TN)  // 16
#define KT_STEPS (D_K / BK)     // 16

#define AS1 __attribute__((address_space(1)))
#define AS3 __attribute__((address_space(3)))

#define WAITVM(N) asm volatile("s_waitcnt vmcnt(" #N ")" ::: "memory")
#define LGKM0 asm volatile("s_waitcnt lgkmcnt(0)" ::: "memory")
#define FENCE asm volatile("" ::: "memory")

// ---- prep: fp32 [rows][1024] -> packed fp8 row + per-row squared norm ----
// Packed byte position within row: seg(=128-K-seg)*128 + (ksp*4+g)*16 + h*8 + j
// where k = 32*(2*ksp+h) + 8*g + j.   (R5 layout, proven R5-R12.)
__global__ __launch_bounds__(256) void rowsq_fp8pack(const float* __restrict__ src,
                                                     unsigned char* __restrict__ dst,
                                                     float* __restrict__ sq) {
  const int m = blockIdx.x;   // row
  const int t = threadIdx.x;  // 256 threads * 4 floats = 1024
  const float4 v = *reinterpret_cast<const float4*>(src + (size_t)m * D_K + t * 4);
  int pk = __builtin_amdgcn_cvt_pk_fp8_f32(v.x, v.y, 0, false);
  pk = __builtin_amdgcn_cvt_pk_fp8_f32(v.z, v.w, pk, true);
  const int k = t * 4;
  const int seg = k >> 7;
  const int ksi = (k >> 5) & 3;
  const int g = (k >> 3) & 3;
  const int j = k & 7;  // 0 or 4
  const int p = seg * 128 + (((ksi >> 1) * 4 + g) << 4) + (ksi & 1) * 8 + j;
  *reinterpret_cast<unsigned int*>(dst + (size_t)m * D_K + p) = (unsigned int)pk;
  float ss = v.x * v.x + v.y * v.y + v.z * v.z + v.w * v.w;
  ss += __shfl_xor(ss, 1);
  ss += __shfl_xor(ss, 2);
  ss += __shfl_xor(ss, 4);
  ss += __shfl_xor(ss, 8);
  ss += __shfl_xor(ss, 16);
  ss += __shfl_xor(ss, 32);
  __shared__ float ws4[4];
  const int w = t >> 6, l = t & 63;
  if (l == 0) ws4[w] = ss;
  __syncthreads();
  if (t == 0) sq[m] = ws4[0] + ws4[1] + ws4[2] + ws4[3];
}

// ---- fast path: MX fp8, 128x128 tile, BK=128, A-in-LDS / B-from-L2 ----
// LDS: A[128 rows][128 B] = 16 KB single buffer (+1 KB rowmin). 3 blk/CU.
// K-tile kt:
//   WAITVM(8) -- retires A-stage(kt) (4 oldest); B(kt) 8 loads stay in
//                flight (compiler vmcnt's them before MFMA use)
//   B1        -- all waves' A(kt) landed (read-safety)
//   compute: 8 ds_read_b128 (A) + preloaded B + 16 mfma_scale
//   [kt<7] LGKM0 -> B2 (A reads done) -> stageA(kt+1) -> FENCE ->
//          loadB(kt+1)  (issue order A-then-B pinned by FENCE)
__global__ __launch_bounds__(256, 3) void gemm_min_mx(const unsigned char* __restrict__ e8,
                                                      const unsigned char* __restrict__ c8,
                                                      const float* __restrict__ csq,
                                                      float* __restrict__ pmin) {
  __shared__ __align__(16) char lds[16384];
  __shared__ float rowmin2[2][BM4];

  const int t = threadIdx.x;
  const int w = t >> 6;
  const int l = t & 63;
  const int wr = w >> 1, wc = w & 1;  // 2x2 wave grid, 64x64 tiles
  const int g = l >> 4, lr = l & 15;

  // XCD swizzle: XCD k owns swz in [1568k,1568k+1568) = rp in [98k,98k+98)
  // x all 16 ct. c8 (2 MB) L2-resident; A panel (128 KB) reused 16x L2-hot.
  const int b = blockIdx.x;
  const int swz = (b & 7) * BPX4 + (b >> 3);
  const int rp = swz >> 4, ct = swz & 15;
  const long row0 = (long)rp * BM4;
  const int col0 = ct * BN4;

  // A staging: dest linear d = i*4096 + t*16 -> row = i*32+(t>>3), slot = t&7
  // (row&7 i-invariant). source = row*1024 + kt*128 + ((slot^(row&7))<<4).
  const int trow = t >> 3, tsl = t & 7;
  const int ssw = (tsl ^ (trow & 7)) << 4;
  const unsigned char* srcA0 = e8 + (row0 + trow) * (size_t)D_K + ssw;
  const int dst0 = t * 16;

  // B direct-from-global column pointers (include g*16 slot offset)
  const unsigned char* colB[4];
#pragma unroll
  for (int n = 0; n < 4; ++n)
    colB[n] = c8 + (size_t)(col0 + wc * 64 + n * 16 + lr) * D_K + g * 16;

  f32x4 acc[4][4];
#pragma unroll
  for (int m = 0; m < 4; ++m)
#pragma unroll
    for (int n = 0; n < 4; ++n) acc[m][n] = (f32x4){0.f, 0.f, 0.f, 0.f};

  // A frag bases: row&7 == lr&7 independent of m/wr -> m-invariant swizzle.
  const int swsel = lr & 7;
  const char* aBase0 = lds + (wr * 64 + lr) * 128 + ((g ^ swsel) << 4);
  const char* aBase1 = lds + (wr * 64 + lr) * 128 + (((4 + g) ^ swsel) << 4);

  i32x4 bLo[4], bHi[4];

  auto stageA = [&](int kt) {
    const size_t ko = (size_t)kt * BK4;
#pragma unroll
    for (int i = 0; i < 4; ++i)
      __builtin_amdgcn_global_load_lds(
          (const AS1 unsigned int*)(const void*)(srcA0 + (size_t)i * 32 * D_K + ko),
          (AS3 unsigned int*)(void*)(lds + i * 4096 + dst0), 16, 0, 0);
  };

  auto loadB = [&](int kt) {
#pragma unroll
    for (int n = 0; n < 4; ++n) {
      bLo[n] = *reinterpret_cast<const i32x4*>(colB[n] + kt * 128);
      bHi[n] = *reinterpret_cast<const i32x4*>(colB[n] + kt * 128 + 64);
    }
  };

  // A from LDS + preloaded B -> 16 mfma_scale (K=128, unit e8m0 scales)
  auto compute_tile = [&]() {
    i32x8 b8[4];
#pragma unroll
    for (int n = 0; n < 4; ++n)
      b8[n] = __builtin_shufflevector(bLo[n], bHi[n], 0, 1, 2, 3, 4, 5, 6, 7);
#pragma unroll
    for (int m = 0; m < 4; ++m) {
      const i32x4 lo = *reinterpret_cast<const i32x4*>(aBase0 + m * 2048);
      const i32x4 hi = *reinterpret_cast<const i32x4*>(aBase1 + m * 2048);
      const i32x8 a8 = __builtin_shufflevector(lo, hi, 0, 1, 2, 3, 4, 5, 6, 7);
#pragma unroll
      for (int n = 0; n < 4; ++n)
        acc[m][n] = __builtin_amdgcn_mfma_scale_f32_16x16x128_f8f6f4(
            a8, b8[n], acc[m][n], 0 /*fp8 A*/, 0 /*fp8 B*/, 0, 0x7F7F7F7F, 0,
            0x7F7F7F7F);
    }
  };

  stageA(0);
  FENCE;
  loadB(0);
#pragma unroll
  for (int kt = 0; kt < NT4; ++kt) {
    WAITVM(8);  // retire the 4 oldest (A-stage kt); B(kt) may stay in flight
    FENCE;
    __builtin_amdgcn_s_barrier();  // B1: A tile kt fully landed (all waves)
    FENCE;
    compute_tile();
    if (kt < NT4 - 1) {
      LGKM0;  // all A ds_reads complete
      FENCE;
      __builtin_amdgcn_s_barrier();  // B2: all waves' A reads done
      FENCE;
      stageA(kt + 1);  // overwrite A buffer (4 loads, oldest in queue)
      FENCE;           // pin issue order: A-stage before B loads
      loadB(kt + 1);   // 8 loads, newest in queue
    }
  }

  // --- partial min over this block's 128 cols: val = ||c||^2 - 2*dot ---
  float runmin[4][4];
#pragma unroll
  for (int m = 0; m < 4; ++m)
#pragma unroll
    for (int r = 0; r < 4; ++r) runmin[m][r] = 3.0e38f;
#pragma unroll
  for (int n = 0; n < 4; ++n) {
    const float cs = csq[col0 + wc * 64 + n * 16 + lr];
#pragma unroll
    for (int m = 0; m < 4; ++m)
#pragma unroll
      for (int r = 0; r < 4; ++r)
        runmin[m][r] = fminf(runmin[m][r], cs - 2.0f * acc[m][n][r]);
  }
#pragma unroll
  for (int m = 0; m < 4; ++m)
#pragma unroll
    for (int r = 0; r < 4; ++r) {
      float v = runmin[m][r];
      v = fminf(v, __shfl_xor(v, 1));
      v = fminf(v, __shfl_xor(v, 2));
      v = fminf(v, __shfl_xor(v, 4));
      v = fminf(v, __shfl_xor(v, 8));
      runmin[m][r] = v;
    }
  if (lr == 0) {
#pragma unroll
    for (int m = 0; m < 4; ++m)
#pragma unroll
      for (int r = 0; r < 4; ++r)
        rowmin2[wc][wr * 64 + m * 16 + g * 4 + r] = runmin[m][r];
  }
  __syncthreads();
  if (t < BM4) {
    pmin[(row0 + t) * NCT4 + ct] = fminf(rowmin2[0][t], rowmin2[1][t]);
  }
}

// ---- final: 16-way min + sqrt ----
__global__ __launch_bounds__(256) void final_min(const float* __restrict__ esq,
                                                 const float* __restrict__ pmin,
                                                 float* __restrict__ out) {
  const int r = blockIdx.x * 256 + threadIdx.x;
  const float4* p = reinterpret_cast<const float4*>(pmin + (size_t)r * 16);
  float4 a = p[0], b = p[1], c = p[2], d = p[3];
  float m = fminf(fminf(fminf(a.x, a.y), fminf(a.z, a.w)),
                  fminf(fminf(b.x, b.y), fminf(b.z, b.w)));
  m = fminf(m, fminf(fminf(fminf(c.x, c.y), fminf(c.z, c.w)),
                     fminf(fminf(d.x, d.y), fminf(d.z, d.w))));
  out[r] = sqrtf(fmaxf(esq[r] + m, 0.f));
}

// ---- bf16 prep (fallback path) ----
__global__ __launch_bounds__(256) void rowsq_bf16(const float* __restrict__ src,
                                                  __bf16* __restrict__ dst,
                                                  float* __restrict__ sq) {
  const int m = blockIdx.x;
  const int t = threadIdx.x;
  const float4 v = *reinterpret_cast<const float4*>(src + (size_t)m * D_K + t * 4);
  bf16x4 o = {(__bf16)v.x, (__bf16)v.y, (__bf16)v.z, (__bf16)v.w};
  *reinterpret_cast<bf16x4*>(dst + (size_t)m * D_K + t * 4) = o;
  float ss = v.x * v.x + v.y * v.y + v.z * v.z + v.w * v.w;
  ss += __shfl_xor(ss, 1);
  ss += __shfl_xor(ss, 2);
  ss += __shfl_xor(ss, 4);
  ss += __shfl_xor(ss, 8);
  ss += __shfl_xor(ss, 16);
  ss += __shfl_xor(ss, 32);
  __shared__ float ws4[4];
  const int w = t >> 6, l = t & 63;
  if (l == 0) ws4[w] = ss;
  __syncthreads();
  if (t == 0) sq[m] = ws4[0] + ws4[1] + ws4[2] + ws4[3];
}

// =================== round-1 fallback (proven) ===================
template <bool WS>
__global__ __launch_bounds__(256, 2) void fused_min(const float* __restrict__ embeds,
                                                    const float* __restrict__ centf,
                                                    const __bf16* __restrict__ cbf,
                                                    const float* __restrict__ csq,
                                                    float* __restrict__ out) {
  __shared__ __align__(16) char Ab[TM * 128];
  __shared__ __align__(16) char Bb[TN * 128];
  __shared__ float rowmin2[2][TM];
  __shared__ float sqrow[TM];
  __shared__ float colsq[TN];

  const int t = threadIdx.x;
  const int w = t >> 6;
  const int l = t & 63;
  const int wr = w >> 1, wc = w & 1;
  const int g = l >> 4, lr = l & 15;
  const long row0 = (long)blockIdx.x * TM;

  float runmin[4][4];
#pragma unroll
  for (int m = 0; m < 4; ++m)
#pragma unroll
    for (int r = 0; r < 4; ++r) runmin[m][r] = 3.0e38f;

  float sqpart[8];
#pragma unroll
  for (int c = 0; c < 8; ++c) sqpart[c] = 0.f;

  for (int nt = 0; nt < NT_TILES; ++nt) {
    const int col0 = nt * TN;
    f32x4 acc[4][4];
#pragma unroll
    for (int m = 0; m < 4; ++m)
#pragma unroll
      for (int n = 0; n < 4; ++n) acc[m][n] = (f32x4){0.f, 0.f, 0.f, 0.f};

    float cpart[8];
    if constexpr (!WS) {
#pragma unroll
      for (int c = 0; c < 8; ++c) cpart[c] = 0.f;
    }

    for (int kt = 0; kt < KT_STEPS; ++kt) {
      __syncthreads();
      if constexpr (WS) {
#pragma unroll
        for (int i = 0; i < 4; ++i) {
          const int s = (w * 4 + i) * 64 + l;
          const int col = s >> 3, sl = s & 7;
          const __bf16* src =
              cbf + (size_t)(col0 + col) * D_K + kt * BK + ((sl ^ (col & 7)) << 3);
          __builtin_amdgcn_global_load_lds(
              (const AS1 unsigned int*)(const void*)src,
              (AS3 unsigned int*)(void*)(Bb + (w * 4 + i) * 1024), 16, 0, 0);
        }
      } else {
#pragma unroll
        for (int c = 0; c < 8; ++c) {
          const int f = c * 256 + t;
          const int col = f >> 4, kq = f & 15;
          const float4 v = *reinterpret_cast<const float4*>(
              centf + (size_t)(col0 + col) * D_K + kt * BK + kq * 4);
          cpart[c] += v.x * v.x + v.y * v.y + v.z * v.z + v.w * v.w;
          bf16x4 o = {(__bf16)v.x, (__bf16)v.y, (__bf16)v.z, (__bf16)v.w};
          const int slot = kq >> 1;
          *reinterpret_cast<bf16x4*>(Bb + col * 128 + ((slot ^ (col & 7)) << 4) +
                                     (kq & 1) * 8) = o;
        }
      }
#pragma unroll
      for (int c = 0; c < 8; ++c) {
        const int f = c * 256 + t;
        const int row = f >> 4, kq = f & 15;
        const float4 v = *reinterpret_cast<const float4*>(
            embeds + (row0 + row) * (long)D_K + kt * BK + kq * 4);
        if (nt == 0) sqpart[c] += v.x * v.x + v.y * v.y + v.z * v.z + v.w * v.w;
        bf16x4 o = {(__bf16)v.x, (__bf16)v.y, (__bf16)v.z, (__bf16)v.w};
        const int slot = kq >> 1;
        *reinterpret_cast<bf16x4*>(Ab + row * 128 + ((slot ^ (row & 7)) << 4) +
                                   (kq & 1) * 8) = o;
      }
      __syncthreads();
#pragma unroll
      for (int ks = 0; ks < 2; ++ks) {
        bf16x8 af[4], bfr[4];
#pragma unroll
        for (int m = 0; m < 4; ++m) {
          const int row = wr * 64 + m * 16 + lr;
          const int slot = ks * 4 + g;
          af[m] = *reinterpret_cast<const bf16x8*>(Ab + row * 128 +
                                                   ((slot ^ (row & 7)) << 4));
        }
#pragma unroll
        for (int n = 0; n < 4; ++n) {
          const int col = wc * 64 + n * 16 + lr;
          const int slot = ks * 4 + g;
          bfr[n] = *reinterpret_cast<const bf16x8*>(Bb + col * 128 +
                                                    ((slot ^ (col & 7)) << 4));
        }
#pragma unroll
        for (int m = 0; m < 4; ++m)
#pragma unroll
          for (int n = 0; n < 4; ++n)
            acc[m][n] =
                __builtin_amdgcn_mfma_f32_16x16x32_bf16(af[m], bfr[n], acc[m][n], 0, 0, 0);
      }
    }

    if (nt == 0) {
#pragma unroll
      for (int c = 0; c < 8; ++c) {
        float ss = sqpart[c];
        ss += __shfl_xor(ss, 1);
        ss += __shfl_xor(ss, 2);
        ss += __shfl_xor(ss, 4);
        ss += __shfl_xor(ss, 8);
        if (lr == 0) sqrow[c * 16 + (w * 4 + g)] = ss;
      }
    }
    if constexpr (!WS) {
#pragma unroll
      for (int c = 0; c < 8; ++c) {
        float ss = cpart[c];
        ss += __shfl_xor(ss, 1);
        ss += __shfl_xor(ss, 2);
        ss += __shfl_xor(ss, 4);
        ss += __shfl_xor(ss, 8);
        if (lr == 0) colsq[c * 16 + (w * 4 + g)] = ss;
      }
      __syncthreads();
    }

#pragma unroll
    for (int n = 0; n < 4; ++n) {
      float cs;
      if constexpr (WS)
        cs = csq[col0 + wc * 64 + n * 16 + lr];
      else
        cs = colsq[wc * 64 + n * 16 + lr];
#pragma unroll
      for (int m = 0; m < 4; ++m)
#pragma unroll
        for (int r = 0; r < 4; ++r)
          runmin[m][r] = fminf(runmin[m][r], cs - 2.0f * acc[m][n][r]);
    }
  }

#pragma unroll
  for (int m = 0; m < 4; ++m)
#pragma unroll
    for (int r = 0; r < 4; ++r) {
      float v = runmin[m][r];
      v = fminf(v, __shfl_xor(v, 1));
      v = fminf(v, __shfl_xor(v, 2));
      v = fminf(v, __shfl_xor(v, 4));
      v = fminf(v, __shfl_xor(v, 8));
      runmin[m][r] = v;
    }
  if (lr == 0) {
#pragma unroll
    for (int m = 0; m < 4; ++m)
#pragma unroll
      for (int r = 0; r < 4; ++r)
        rowmin2[wc][wr * 64 + m * 16 + g * 4 + r] = runmin[m][r];
  }
  __syncthreads();
  if (t < TM) {
    const float v = fminf(rowmin2[0][t], rowmin2[1][t]);
    out[row0 + t] = sqrtf(fmaxf(sqrow[t] + v, 0.f));
  }
}

extern "C" void kernel_launch(void* const* d_in, const int* in_sizes, int n_in,
                              void* d_out, int out_size, void* d_ws, size_t ws_size,
                              hipStream_t stream) {
  const float* embeds = (const float*)d_in[0];
  const float* cent = (const float*)d_in[1];
  float* out = (float*)d_out;

  // ws layout for the fp8 fast path (~112 MiB)
  const size_t off_c8 = 0;
  const size_t off_csq = off_c8 + (size_t)M_CENT * D_K;             // 2 MiB
  const size_t off_e8 = off_csq + (size_t)M_CENT * 4;               // +8 KiB
  const size_t off_esq = off_e8 + (size_t)N_ROWS * D_K;             // +98 MiB
  const size_t off_pmin = off_esq + (size_t)N_ROWS * 4;             // +392 KiB
  const size_t need_full = off_pmin + (size_t)N_ROWS * NCT4 * 4;    // +6.1 MiB
  const size_t need_small = (size_t)M_CENT * D_K * 2 + (size_t)M_CENT * 4;

  if (ws_size >= need_full) {
    unsigned char* c8 = (unsigned char*)d_ws + off_c8;
    float* csq = (float*)((char*)d_ws + off_csq);
    unsigned char* e8 = (unsigned char*)d_ws + off_e8;
    float* esq = (float*)((char*)d_ws + off_esq);
    float* pmin = (float*)((char*)d_ws + off_pmin);
    rowsq_fp8pack<<<M_CENT, 256, 0, stream>>>(cent, c8, csq);
    rowsq_fp8pack<<<N_ROWS, 256, 0, stream>>>(embeds, e8, esq);
    gemm_min_mx<<<NBLK4, 256, 0, stream>>>(e8, c8, csq, pmin);
    final_min<<<N_ROWS / 256, 256, 0, stream>>>(esq, pmin, out);
  } else if (ws_size >= need_small) {
    __bf16* cbf = (__bf16*)d_ws;
    float* csq = (float*)((char*)d_ws + (size_t)M_CENT * D_K * 2);
    rowsq_bf16<<<M_CENT, 256, 0, stream>>>(cent, cbf, csq);
    fused_min<true><<<N_ROWS / TM, 256, 0, stream>>>(embeds, cent, cbf, csq, out);
  } else {
    fused_min<false><<<N_ROWS / TM, 256, 0, stream>>>(embeds, cent, nullptr, nullptr, out);
  }
}

// Round 14
// 323.204 us; speedup vs baseline: 1.5299x; 1.5299x over previous
//
#include <hip/hip_runtime.h>
#include <hip/hip_bf16.h>

// CentroidsFlowAD: out[row] = sqrt(max(||e||^2 + min_col(||c||^2 - 2 e.c), 0))
// rows = 32*3136 = 100352, cols = 2048 centroids, K = 1024.
//
// Fast path (needs ~112 MiB ws), fp8 e4m3 cross-term (row norms exact fp32):
//   1. rowsq_fp8packT on centroids -> c8t (TRANSPOSED fragment-major fp8)
//      + csq. Layout: byte ((seg*8+slot)*2048 + col)*16 + b -- a wave's
//      B-frag load is 64 lanes x 16B CONSECUTIVE = one coalesced 1KB
//      transaction (R13's direct-B failed only because row-major c8 made
//      each lane-load touch 64 cache lines: transaction-bound, MfmaUtil 20%).
//   2. rowsq_fp8pack on embeds -> e8 (row-major seg-128 layout) + esq
//   3. gemm_min_mx: 128x128 tile, BK=128, 4 waves (64x64), MX-scaled
//      mfma_scale 16x16x128 (unit e8m0; layout verified R9-R13).
//      A in LDS (16 KB single buffer), B DIRECT from L2 (c8t, coalesced)
//      -> LDS traffic halved (floor 142->~75 us). 3 blocks/CU at
//      launch_bounds(256,3) (R11 no-spill sweet spot; R12: TLP > dbuf).
//      Schedule: WAITVM(8) retires A-stage (4 oldest, FENCE-pinned
//      A-before-B) -> B1 -> compute (B regs: compiler vmcnts before MFMA)
//      -> LGKM0 -> B2 -> stageA(kt+1) -> loadB(kt+1).
//   4. final_min: 16-way min + sqrt
// e8 row layout (128B per K-seg): 16B slot s=ksp*4+g holds
// k = {32*(2ksp)+8g..+7 | 32*(2ksp+1)+8g..+7}; A slot swizzle s^(row&7).
// Fallback: round-1 fused kernel (proven, bf16).

typedef __bf16 bf16x8 __attribute__((ext_vector_type(8)));
typedef __bf16 bf16x4 __attribute__((ext_vector_type(4)));
typedef float f32x4 __attribute__((ext_vector_type(4)));
typedef int i32x4 __attribute__((ext_vector_type(4)));
typedef int i32x8 __attribute__((ext_vector_type(8)));

#define N_ROWS 100352
#define M_CENT 2048
#define D_K 1024

// fp8 fast-path geometry
#define BM4 128
#define BN4 128
#define BK4 128
#define NT4 (D_K / BK4)                // 8 K-tiles
#define NCT4 (M_CENT / BN4)            // 16 col tiles
#define NBLK4 ((N_ROWS / BM4) * NCT4)  // 12544
#define BPX4 (NBLK4 / 8)               // 1568 per XCD

// fallback geometry (round-1, unchanged)
#define TM 128
#define TN 128
#define BK 64
#define NT_TILES (M_CENT / TN)  // 16
#define KT_STEPS (D_K / BK)     // 16

#define AS1 __attribute__((address_space(1)))
#define AS3 __attribute__((address_space(3)))

#define WAITVM(N) asm volatile("s_waitcnt vmcnt(" #N ")" ::: "memory")
#define LGKM0 asm volatile("s_waitcnt lgkmcnt(0)" ::: "memory")
#define FENCE asm volatile("" ::: "memory")

// ---- prep (embeds): fp32 [rows][1024] -> packed fp8 row + row sqnorm ----
// Byte pos in row: seg*128 + (ksp*4+g)*16 + h*8 + j, k = 32*(2ksp+h)+8g+j.
__global__ __launch_bounds__(256) void rowsq_fp8pack(const float* __restrict__ src,
                                                     unsigned char* __restrict__ dst,
                                                     float* __restrict__ sq) {
  const int m = blockIdx.x;   // row
  const int t = threadIdx.x;  // 256 threads * 4 floats = 1024
  const float4 v = *reinterpret_cast<const float4*>(src + (size_t)m * D_K + t * 4);
  int pk = __builtin_amdgcn_cvt_pk_fp8_f32(v.x, v.y, 0, false);
  pk = __builtin_amdgcn_cvt_pk_fp8_f32(v.z, v.w, pk, true);
  const int k = t * 4;
  const int seg = k >> 7;
  const int ksi = (k >> 5) & 3;
  const int g = (k >> 3) & 3;
  const int j = k & 7;  // 0 or 4
  const int p = seg * 128 + (((ksi >> 1) * 4 + g) << 4) + (ksi & 1) * 8 + j;
  *reinterpret_cast<unsigned int*>(dst + (size_t)m * D_K + p) = (unsigned int)pk;
  float ss = v.x * v.x + v.y * v.y + v.z * v.z + v.w * v.w;
  ss += __shfl_xor(ss, 1);
  ss += __shfl_xor(ss, 2);
  ss += __shfl_xor(ss, 4);
  ss += __shfl_xor(ss, 8);
  ss += __shfl_xor(ss, 16);
  ss += __shfl_xor(ss, 32);
  __shared__ float ws4[4];
  const int w = t >> 6, l = t & 63;
  if (l == 0) ws4[w] = ss;
  __syncthreads();
  if (t == 0) sq[m] = ws4[0] + ws4[1] + ws4[2] + ws4[3];
}

// ---- prep (centroids): fp32 -> TRANSPOSED fragment-major fp8 + sqnorm ----
// dst byte = ((seg*8 + s)*2048 + m)*16 + h*8 + j, s = ksp*4+g.
// Same 16B content per (seg,s,row) as the row-major layout; only placement
// differs -> B-frag loads are lane-coalesced.
__global__ __launch_bounds__(256) void rowsq_fp8packT(const float* __restrict__ src,
                                                      unsigned char* __restrict__ dst,
                                                      float* __restrict__ sq) {
  const int m = blockIdx.x;   // centroid (becomes column)
  const int t = threadIdx.x;
  const float4 v = *reinterpret_cast<const float4*>(src + (size_t)m * D_K + t * 4);
  int pk = __builtin_amdgcn_cvt_pk_fp8_f32(v.x, v.y, 0, false);
  pk = __builtin_amdgcn_cvt_pk_fp8_f32(v.z, v.w, pk, true);
  const int k = t * 4;
  const int seg = k >> 7;
  const int ksi = (k >> 5) & 3;
  const int g = (k >> 3) & 3;
  const int j = k & 7;  // 0 or 4
  const int s = (ksi >> 1) * 4 + g;
  const size_t p = ((size_t)(seg * 8 + s) * 2048 + m) * 16 + (ksi & 1) * 8 + j;
  *reinterpret_cast<unsigned int*>(dst + p) = (unsigned int)pk;
  float ss = v.x * v.x + v.y * v.y + v.z * v.z + v.w * v.w;
  ss += __shfl_xor(ss, 1);
  ss += __shfl_xor(ss, 2);
  ss += __shfl_xor(ss, 4);
  ss += __shfl_xor(ss, 8);
  ss += __shfl_xor(ss, 16);
  ss += __shfl_xor(ss, 32);
  __shared__ float ws4[4];
  const int w = t >> 6, l = t & 63;
  if (l == 0) ws4[w] = ss;
  __syncthreads();
  if (t == 0) sq[m] = ws4[0] + ws4[1] + ws4[2] + ws4[3];
}

// ---- fast path: MX fp8, A-in-LDS / B-from-L2 (coalesced), 3 blk/CU ----
// LDS: A[128 rows][128 B] = 16 KB single buffer (+1 KB rowmin).
// K-tile kt:
//   WAITVM(8) -- retires A-stage(kt) (4 oldest; A-before-B FENCE-pinned);
//                B(kt) regs get compiler-precise vmcnt before MFMA use
//   B1        -- all waves' A(kt) landed (read-safety)
//   compute: 8 ds_read_b128 (A) + B regs -> 16 mfma_scale
//   [kt<7] LGKM0 -> B2 (A reads done) -> stageA(kt+1) -> FENCE ->
//          loadB(kt+1) (coalesced 1KB x 8)
__global__ __launch_bounds__(256, 3) void gemm_min_mx(const unsigned char* __restrict__ e8,
                                                      const unsigned char* __restrict__ c8t,
                                                      const float* __restrict__ csq,
                                                      float* __restrict__ pmin) {
  __shared__ __align__(16) char lds[16384];
  __shared__ float rowmin2[2][BM4];

  const int t = threadIdx.x;
  const int w = t >> 6;
  const int l = t & 63;
  const int wr = w >> 1, wc = w & 1;  // 2x2 wave grid, 64x64 tiles
  const int g = l >> 4, lr = l & 15;

  // XCD swizzle: XCD k owns swz in [1568k,1568k+1568) = rp in [98k,98k+98)
  // x all 16 ct. c8t (2 MB) L2-resident; A panel (128 KB) reused 16x L2-hot.
  const int b = blockIdx.x;
  const int swz = (b & 7) * BPX4 + (b >> 3);
  const int rp = swz >> 4, ct = swz & 15;
  const long row0 = (long)rp * BM4;
  const int col0 = ct * BN4;

  // A staging: dest linear d = i*4096 + t*16 -> row = i*32+(t>>3), slot = t&7
  // (row&7 i-invariant). source = row*1024 + kt*128 + ((slot^(row&7))<<4).
  const int trow = t >> 3, tsl = t & 7;
  const int ssw = (tsl ^ (trow & 7)) << 4;
  const unsigned char* srcA0 = e8 + (row0 + trow) * (size_t)D_K + ssw;
  const int dst0 = t * 16;

  // B direct pointers into c8t: frag (n, ksp) at
  //   ((kt*8 + ksp*4 + g)*2048 + col)*16  with col = col0+wc*64+n*16+lr.
  // colp[n] folds the col*16 and g*2048*16 terms; kt/ksp are immediates
  // after unroll (kt*256KB + ksp*128KB).
  const unsigned char* colp[4];
#pragma unroll
  for (int n = 0; n < 4; ++n)
    colp[n] = c8t + ((size_t)g * 2048 + (col0 + wc * 64 + n * 16 + lr)) * 16;

  f32x4 acc[4][4];
#pragma unroll
  for (int m = 0; m < 4; ++m)
#pragma unroll
    for (int n = 0; n < 4; ++n) acc[m][n] = (f32x4){0.f, 0.f, 0.f, 0.f};

  // A frag bases: row&7 == lr&7 independent of m/wr -> m-invariant swizzle.
  const int swsel = lr & 7;
  const char* aBase0 = lds + (wr * 64 + lr) * 128 + ((g ^ swsel) << 4);
  const char* aBase1 = lds + (wr * 64 + lr) * 128 + (((4 + g) ^ swsel) << 4);

  i32x4 bLo[4], bHi[4];

  auto stageA = [&](int kt) {
    const size_t ko = (size_t)kt * BK4;
#pragma unroll
    for (int i = 0; i < 4; ++i)
      __builtin_amdgcn_global_load_lds(
          (const AS1 unsigned int*)(const void*)(srcA0 + (size_t)i * 32 * D_K + ko),
          (AS3 unsigned int*)(void*)(lds + i * 4096 + dst0), 16, 0, 0);
  };

  auto loadB = [&](int kt) {
#pragma unroll
    for (int n = 0; n < 4; ++n) {
      bLo[n] = *reinterpret_cast<const i32x4*>(colp[n] + (size_t)kt * 262144);
      bHi[n] = *reinterpret_cast<const i32x4*>(colp[n] + (size_t)kt * 262144 + 131072);
    }
  };

  // A from LDS + preloaded B -> 16 mfma_scale (K=128, unit e8m0 scales)
  auto compute_tile = [&]() {
    i32x8 b8[4];
#pragma unroll
    for (int n = 0; n < 4; ++n)
      b8[n] = __builtin_shufflevector(bLo[n], bHi[n], 0, 1, 2, 3, 4, 5, 6, 7);
#pragma unroll
    for (int m = 0; m < 4; ++m) {
      const i32x4 lo = *reinterpret_cast<const i32x4*>(aBase0 + m * 2048);
      const i32x4 hi = *reinterpret_cast<const i32x4*>(aBase1 + m * 2048);
      const i32x8 a8 = __builtin_shufflevector(lo, hi, 0, 1, 2, 3, 4, 5, 6, 7);
#pragma unroll
      for (int n = 0; n < 4; ++n)
        acc[m][n] = __builtin_amdgcn_mfma_scale_f32_16x16x128_f8f6f4(
            a8, b8[n], acc[m][n], 0 /*fp8 A*/, 0 /*fp8 B*/, 0, 0x7F7F7F7F, 0,
            0x7F7F7F7F);
    }
  };

  stageA(0);
  FENCE;  // pin issue order: A-stage first (oldest in vmcnt queue)
  loadB(0);
#pragma unroll
  for (int kt = 0; kt < NT4; ++kt) {
    WAITVM(8);  // retire the 4 oldest (A-stage kt); B may stay in flight
    FENCE;
    __builtin_amdgcn_s_barrier();  // B1: A tile kt fully landed (all waves)
    FENCE;
    compute_tile();
    if (kt < NT4 - 1) {
      LGKM0;  // all A ds_reads complete
      FENCE;
      __builtin_amdgcn_s_barrier();  // B2: all waves' A reads done
      FENCE;
      stageA(kt + 1);  // overwrite A buffer (4 loads, oldest in queue)
      FENCE;           // pin issue order: A-stage before B loads
      loadB(kt + 1);   // 8 coalesced loads, newest in queue
    }
  }

  // --- partial min over this block's 128 cols: val = ||c||^2 - 2*dot ---
  float runmin[4][4];
#pragma unroll
  for (int m = 0; m < 4; ++m)
#pragma unroll
    for (int r = 0; r < 4; ++r) runmin[m][r] = 3.0e38f;
#pragma unroll
  for (int n = 0; n < 4; ++n) {
    const float cs = csq[col0 + wc * 64 + n * 16 + lr];
#pragma unroll
    for (int m = 0; m < 4; ++m)
#pragma unroll
      for (int r = 0; r < 4; ++r)
        runmin[m][r] = fminf(runmin[m][r], cs - 2.0f * acc[m][n][r]);
  }
#pragma unroll
  for (int m = 0; m < 4; ++m)
#pragma unroll
    for (int r = 0; r < 4; ++r) {
      float v = runmin[m][r];
      v = fminf(v, __shfl_xor(v, 1));
      v = fminf(v, __shfl_xor(v, 2));
      v = fminf(v, __shfl_xor(v, 4));
      v = fminf(v, __shfl_xor(v, 8));
      runmin[m][r] = v;
    }
  if (lr == 0) {
#pragma unroll
    for (int m = 0; m < 4; ++m)
#pragma unroll
      for (int r = 0; r < 4; ++r)
        rowmin2[wc][wr * 64 + m * 16 + g * 4 + r] = runmin[m][r];
  }
  __syncthreads();
  if (t < BM4) {
    pmin[(row0 + t) * NCT4 + ct] = fminf(rowmin2[0][t], rowmin2[1][t]);
  }
}

// ---- final: 16-way min + sqrt ----
__global__ __launch_bounds__(256) void final_min(const float* __restrict__ esq,
                                                 const float* __restrict__ pmin,
                                                 float* __restrict__ out) {
  const int r = blockIdx.x * 256 + threadIdx.x;
  const float4* p = reinterpret_cast<const float4*>(pmin + (size_t)r * 16);
  float4 a = p[0], b = p[1], c = p[2], d = p[3];
  float m = fminf(fminf(fminf(a.x, a.y), fminf(a.z, a.w)),
                  fminf(fminf(b.x, b.y), fminf(b.z, b.w)));
  m = fminf(m, fminf(fminf(fminf(c.x, c.y), fminf(c.z, c.w)),
                     fminf(fminf(d.x, d.y), fminf(d.z, d.w))));
  out[r] = sqrtf(fmaxf(esq[r] + m, 0.f));
}

// ---- bf16 prep (fallback path) ----
__global__ __launch_bounds__(256) void rowsq_bf16(const float* __restrict__ src,
                                                  __bf16* __restrict__ dst,
                                                  float* __restrict__ sq) {
  const int m = blockIdx.x;
  const int t = threadIdx.x;
  const float4 v = *reinterpret_cast<const float4*>(src + (size_t)m * D_K + t * 4);
  bf16x4 o = {(__bf16)v.x, (__bf16)v.y, (__bf16)v.z, (__bf16)v.w};
  *reinterpret_cast<bf16x4*>(dst + (size_t)m * D_K + t * 4) = o;
  float ss = v.x * v.x + v.y * v.y + v.z * v.z + v.w * v.w;
  ss += __shfl_xor(ss, 1);
  ss += __shfl_xor(ss, 2);
  ss += __shfl_xor(ss, 4);
  ss += __shfl_xor(ss, 8);
  ss += __shfl_xor(ss, 16);
  ss += __shfl_xor(ss, 32);
  __shared__ float ws4[4];
  const int w = t >> 6, l = t & 63;
  if (l == 0) ws4[w] = ss;
  __syncthreads();
  if (t == 0) sq[m] = ws4[0] + ws4[1] + ws4[2] + ws4[3];
}

// =================== round-1 fallback (proven) ===================
template <bool WS>
__global__ __launch_bounds__(256, 2) void fused_min(const float* __restrict__ embeds,
                                                    const float* __restrict__ centf,
                                                    const __bf16* __restrict__ cbf,
                                                    const float* __restrict__ csq,
                                                    float* __restrict__ out) {
  __shared__ __align__(16) char Ab[TM * 128];
  __shared__ __align__(16) char Bb[TN * 128];
  __shared__ float rowmin2[2][TM];
  __shared__ float sqrow[TM];
  __shared__ float colsq[TN];

  const int t = threadIdx.x;
  const int w = t >> 6;
  const int l = t & 63;
  const int wr = w >> 1, wc = w & 1;
  const int g = l >> 4, lr = l & 15;
  const long row0 = (long)blockIdx.x * TM;

  float runmin[4][4];
#pragma unroll
  for (int m = 0; m < 4; ++m)
#pragma unroll
    for (int r = 0; r < 4; ++r) runmin[m][r] = 3.0e38f;

  float sqpart[8];
#pragma unroll
  for (int c = 0; c < 8; ++c) sqpart[c] = 0.f;

  for (int nt = 0; nt < NT_TILES; ++nt) {
    const int col0 = nt * TN;
    f32x4 acc[4][4];
#pragma unroll
    for (int m = 0; m < 4; ++m)
#pragma unroll
      for (int n = 0; n < 4; ++n) acc[m][n] = (f32x4){0.f, 0.f, 0.f, 0.f};

    float cpart[8];
    if constexpr (!WS) {
#pragma unroll
      for (int c = 0; c < 8; ++c) cpart[c] = 0.f;
    }

    for (int kt = 0; kt < KT_STEPS; ++kt) {
      __syncthreads();
      if constexpr (WS) {
#pragma unroll
        for (int i = 0; i < 4; ++i) {
          const int s = (w * 4 + i) * 64 + l;
          const int col = s >> 3, sl = s & 7;
          const __bf16* src =
              cbf + (size_t)(col0 + col) * D_K + kt * BK + ((sl ^ (col & 7)) << 3);
          __builtin_amdgcn_global_load_lds(
              (const AS1 unsigned int*)(const void*)src,
              (AS3 unsigned int*)(void*)(Bb + (w * 4 + i) * 1024), 16, 0, 0);
        }
      } else {
#pragma unroll
        for (int c = 0; c < 8; ++c) {
          const int f = c * 256 + t;
          const int col = f >> 4, kq = f & 15;
          const float4 v = *reinterpret_cast<const float4*>(
              centf + (size_t)(col0 + col) * D_K + kt * BK + kq * 4);
          cpart[c] += v.x * v.x + v.y * v.y + v.z * v.z + v.w * v.w;
          bf16x4 o = {(__bf16)v.x, (__bf16)v.y, (__bf16)v.z, (__bf16)v.w};
          const int slot = kq >> 1;
          *reinterpret_cast<bf16x4*>(Bb + col * 128 + ((slot ^ (col & 7)) << 4) +
                                     (kq & 1) * 8) = o;
        }
      }
#pragma unroll
      for (int c = 0; c < 8; ++c) {
        const int f = c * 256 + t;
        const int row = f >> 4, kq = f & 15;
        const float4 v = *reinterpret_cast<const float4*>(
            embeds + (row0 + row) * (long)D_K + kt * BK + kq * 4);
        if (nt == 0) sqpart[c] += v.x * v.x + v.y * v.y + v.z * v.z + v.w * v.w;
        bf16x4 o = {(__bf16)v.x, (__bf16)v.y, (__bf16)v.z, (__bf16)v.w};
        const int slot = kq >> 1;
        *reinterpret_cast<bf16x4*>(Ab + row * 128 + ((slot ^ (row & 7)) << 4) +
                                   (kq & 1) * 8) = o;
      }
      __syncthreads();
#pragma unroll
      for (int ks = 0; ks < 2; ++ks) {
        bf16x8 af[4], bfr[4];
#pragma unroll
        for (int m = 0; m < 4; ++m) {
          const int row = wr * 64 + m * 16 + lr;
          const int slot = ks * 4 + g;
          af[m] = *reinterpret_cast<const bf16x8*>(Ab + row * 128 +
                                                   ((slot ^ (row & 7)) << 4));
        }
#pragma unroll
        for (int n = 0; n < 4; ++n) {
          const int col = wc * 64 + n * 16 + lr;
          const int slot = ks * 4 + g;
          bfr[n] = *reinterpret_cast<const bf16x8*>(Bb + col * 128 +
                                                    ((slot ^ (col & 7)) << 4));
        }
#pragma unroll
        for (int m = 0; m < 4; ++m)
#pragma unroll
          for (int n = 0; n < 4; ++n)
            acc[m][n] =
                __builtin_amdgcn_mfma_f32_16x16x32_bf16(af[m], bfr[n], acc[m][n], 0, 0, 0);
      }
    }

    if (nt == 0) {
#pragma unroll
      for (int c = 0; c < 8; ++c) {
        float ss = sqpart[c];
        ss += __shfl_xor(ss, 1);
        ss += __shfl_xor(ss, 2);
        ss += __shfl_xor(ss, 4);
        ss += __shfl_xor(ss, 8);
        if (lr == 0) sqrow[c * 16 + (w * 4 + g)] = ss;
      }
    }
    if constexpr (!WS) {
#pragma unroll
      for (int c = 0; c < 8; ++c) {
        float ss = cpart[c];
        ss += __shfl_xor(ss, 1);
        ss += __shfl_xor(ss, 2);
        ss += __shfl_xor(ss, 4);
        ss += __shfl_xor(ss, 8);
        if (lr == 0) colsq[c * 16 + (w * 4 + g)] = ss;
      }
      __syncthreads();
    }

#pragma unroll
    for (int n = 0; n < 4; ++n) {
      float cs;
      if constexpr (WS)
        cs = csq[col0 + wc * 64 + n * 16 + lr];
      else
        cs = colsq[wc * 64 + n * 16 + lr];
#pragma unroll
      for (int m = 0; m < 4; ++m)
#pragma unroll
        for (int r = 0; r < 4; ++r)
          runmin[m][r] = fminf(runmin[m][r], cs - 2.0f * acc[m][n][r]);
    }
  }

#pragma unroll
  for (int m = 0; m < 4; ++m)
#pragma unroll
    for (int r = 0; r < 4; ++r) {
      float v = runmin[m][r];
      v = fminf(v, __shfl_xor(v, 1));
      v = fminf(v, __shfl_xor(v, 2));
      v = fminf(v, __shfl_xor(v, 4));
      v = fminf(v, __shfl_xor(v, 8));
      runmin[m][r] = v;
    }
  if (lr == 0) {
#pragma unroll
    for (int m = 0; m < 4; ++m)
#pragma unroll
      for (int r = 0; r < 4; ++r)
        rowmin2[wc][wr * 64 + m * 16 + g * 4 + r] = runmin[m][r];
  }
  __syncthreads();
  if (t < TM) {
    const float v = fminf(rowmin2[0][t], rowmin2[1][t]);
    out[row0 + t] = sqrtf(fmaxf(sqrow[t] + v, 0.f));
  }
}

extern "C" void kernel_launch(void* const* d_in, const int* in_sizes, int n_in,
                              void* d_out, int out_size, void* d_ws, size_t ws_size,
                              hipStream_t stream) {
  const float* embeds = (const float*)d_in[0];
  const float* cent = (const float*)d_in[1];
  float* out = (float*)d_out;

  // ws layout for the fp8 fast path (~112 MiB)
  const size_t off_c8 = 0;
  const size_t off_csq = off_c8 + (size_t)M_CENT * D_K;             // 2 MiB
  const size_t off_e8 = off_csq + (size_t)M_CENT * 4;               // +8 KiB
  const size_t off_esq = off_e8 + (size_t)N_ROWS * D_K;             // +98 MiB
  const size_t off_pmin = off_esq + (size_t)N_ROWS * 4;             // +392 KiB
  const size_t need_full = off_pmin + (size_t)N_ROWS * NCT4 * 4;    // +6.1 MiB
  const size_t need_small = (size_t)M_CENT * D_K * 2 + (size_t)M_CENT * 4;

  if (ws_size >= need_full) {
    unsigned char* c8t = (unsigned char*)d_ws + off_c8;
    float* csq = (float*)((char*)d_ws + off_csq);
    unsigned char* e8 = (unsigned char*)d_ws + off_e8;
    float* esq = (float*)((char*)d_ws + off_esq);
    float* pmin = (float*)((char*)d_ws + off_pmin);
    rowsq_fp8packT<<<M_CENT, 256, 0, stream>>>(cent, c8t, csq);
    rowsq_fp8pack<<<N_ROWS, 256, 0, stream>>>(embeds, e8, esq);
    gemm_min_mx<<<NBLK4, 256, 0, stream>>>(e8, c8t, csq, pmin);
    final_min<<<N_ROWS / 256, 256, 0, stream>>>(esq, pmin, out);
  } else if (ws_size >= need_small) {
    __bf16* cbf = (__bf16*)d_ws;
    float* csq = (float*)((char*)d_ws + (size_t)M_CENT * D_K * 2);
    rowsq_bf16<<<M_CENT, 256, 0, stream>>>(cent, cbf, csq);
    fused_min<true><<<N_ROWS / TM, 256, 0, stream>>>(embeds, cent, cbf, csq, out);
  } else {
    fused_min<false><<<N_ROWS / TM, 256, 0, stream>>>(embeds, cent, nullptr, nullptr, out);
  }
}

// Round 15
// 321.118 us; speedup vs baseline: 1.5398x; 1.0065x over previous
//
#include <hip/hip_runtime.h>
#include <hip/hip_bf16.h>

// CentroidsFlowAD: out[row] = sqrt(max(||e||^2 + min_col(||c||^2 - 2 e.c), 0))
// rows = 32*3136 = 100352, cols = 2048 centroids, K = 1024.
//
// Fast path (needs ~112 MiB ws), fp8 e4m3 cross-term (row norms exact fp32):
//   1. rowsq_fp8packT on centroids -> c8t (transposed fragment-major) + csq
//   2. rowsq_fp8pack on embeds -> e8 (row-major seg-128) + esq
//   3. gemm_min_mx: 128x128 tile, BK=128, MX-scaled mfma_scale 16x16x128.
//      A in LDS, B direct from L2 via c8t (R14, coalesced, verified).
//      R15: A DOUBLE-buffered (2x16 KB) -> ONE barrier per K-tile.
//      R14 diagnosis: latency/sync-bound (no pipe >40% busy; 3 waves/SIMD
//      can't cover a ~4600-cyc per-block chain with 2 barriers + 2 waits
//      per tile). A-dbuf removes B2+LGKM0: stageA(kt+1) targets buf^1,
//      whose readers (compute kt-1) provably finished before B1(kt)
//      (compiler lgkm before MFMA issue precedes barrier arrival).
//      Schedule: WAITVM(8) -> B1 -> stageA(kt+1) -> compute(kt) ->
//      loadB(kt+1). 3 blocks/CU at (256,3) (no spill; R9/R10 lesson).
//   4. final_min: 16-way min + sqrt
// e8 row layout (128B per K-seg): slot s=ksp*4+g holds
// k = {32*(2ksp)+8g..+7 | 32*(2ksp+1)+8g..+7}; A slot swizzle s^(row&7).
// c8t: byte ((seg*8+s)*2048 + col)*16 + b -> B-frag loads lane-coalesced.
// Fallback: round-1 fused kernel (proven, bf16).

typedef __bf16 bf16x8 __attribute__((ext_vector_type(8)));
typedef __bf16 bf16x4 __attribute__((ext_vector_type(4)));
typedef float f32x4 __attribute__((ext_vector_type(4)));
typedef int i32x4 __attribute__((ext_vector_type(4)));
typedef int i32x8 __attribute__((ext_vector_type(8)));

#define N_ROWS 100352
#define M_CENT 2048
#define D_K 1024

// fp8 fast-path geometry
#define BM4 128
#define BN4 128
#define BK4 128
#define NT4 (D_K / BK4)                // 8 K-tiles
#define NCT4 (M_CENT / BN4)            // 16 col tiles
#define NBLK4 ((N_ROWS / BM4) * NCT4)  // 12544
#define BPX4 (NBLK4 / 8)               // 1568 per XCD
#define ABUF 16384                     // one A buffer

// fallback geometry (round-1, unchanged)
#define TM 128
#define TN 128
#define BK 64
#define NT_TILES (M_CENT / TN)  // 16
#define KT_STEPS (D_K / BK)     // 16

#define AS1 __attribute__((address_space(1)))
#define AS3 __attribute__((address_space(3)))

#define WAITVM(N) asm volatile("s_waitcnt vmcnt(" #N ")" ::: "memory")
#define FENCE asm volatile("" ::: "memory")

// ---- prep (embeds): fp32 [rows][1024] -> packed fp8 row + row sqnorm ----
// Byte pos in row: seg*128 + (ksp*4+g)*16 + h*8 + j, k = 32*(2ksp+h)+8g+j.
__global__ __launch_bounds__(256) void rowsq_fp8pack(const float* __restrict__ src,
                                                     unsigned char* __restrict__ dst,
                                                     float* __restrict__ sq) {
  const int m = blockIdx.x;   // row
  const int t = threadIdx.x;  // 256 threads * 4 floats = 1024
  const float4 v = *reinterpret_cast<const float4*>(src + (size_t)m * D_K + t * 4);
  int pk = __builtin_amdgcn_cvt_pk_fp8_f32(v.x, v.y, 0, false);
  pk = __builtin_amdgcn_cvt_pk_fp8_f32(v.z, v.w, pk, true);
  const int k = t * 4;
  const int seg = k >> 7;
  const int ksi = (k >> 5) & 3;
  const int g = (k >> 3) & 3;
  const int j = k & 7;  // 0 or 4
  const int p = seg * 128 + (((ksi >> 1) * 4 + g) << 4) + (ksi & 1) * 8 + j;
  *reinterpret_cast<unsigned int*>(dst + (size_t)m * D_K + p) = (unsigned int)pk;
  float ss = v.x * v.x + v.y * v.y + v.z * v.z + v.w * v.w;
  ss += __shfl_xor(ss, 1);
  ss += __shfl_xor(ss, 2);
  ss += __shfl_xor(ss, 4);
  ss += __shfl_xor(ss, 8);
  ss += __shfl_xor(ss, 16);
  ss += __shfl_xor(ss, 32);
  __shared__ float ws4[4];
  const int w = t >> 6, l = t & 63;
  if (l == 0) ws4[w] = ss;
  __syncthreads();
  if (t == 0) sq[m] = ws4[0] + ws4[1] + ws4[2] + ws4[3];
}

// ---- prep (centroids): fp32 -> TRANSPOSED fragment-major fp8 + sqnorm ----
// dst byte = ((seg*8 + s)*2048 + m)*16 + h*8 + j, s = ksp*4+g.
__global__ __launch_bounds__(256) void rowsq_fp8packT(const float* __restrict__ src,
                                                      unsigned char* __restrict__ dst,
                                                      float* __restrict__ sq) {
  const int m = blockIdx.x;   // centroid (becomes column)
  const int t = threadIdx.x;
  const float4 v = *reinterpret_cast<const float4*>(src + (size_t)m * D_K + t * 4);
  int pk = __builtin_amdgcn_cvt_pk_fp8_f32(v.x, v.y, 0, false);
  pk = __builtin_amdgcn_cvt_pk_fp8_f32(v.z, v.w, pk, true);
  const int k = t * 4;
  const int seg = k >> 7;
  const int ksi = (k >> 5) & 3;
  const int g = (k >> 3) & 3;
  const int j = k & 7;  // 0 or 4
  const int s = (ksi >> 1) * 4 + g;
  const size_t p = ((size_t)(seg * 8 + s) * 2048 + m) * 16 + (ksi & 1) * 8 + j;
  *reinterpret_cast<unsigned int*>(dst + p) = (unsigned int)pk;
  float ss = v.x * v.x + v.y * v.y + v.z * v.z + v.w * v.w;
  ss += __shfl_xor(ss, 1);
  ss += __shfl_xor(ss, 2);
  ss += __shfl_xor(ss, 4);
  ss += __shfl_xor(ss, 8);
  ss += __shfl_xor(ss, 16);
  ss += __shfl_xor(ss, 32);
  __shared__ float ws4[4];
  const int w = t >> 6, l = t & 63;
  if (l == 0) ws4[w] = ss;
  __syncthreads();
  if (t == 0) sq[m] = ws4[0] + ws4[1] + ws4[2] + ws4[3];
}

// ---- fast path: MX fp8, A-dbuf-LDS / B-from-L2, ONE barrier per tile ----
// LDS: 2 x A[128][128B] = 32 KB (+1 KB rowmin). 3 blocks/CU.
// K-tile kt (buf = kt&1):
//   WAITVM(8) -- retires stageA(kt) (4 oldest); B(kt) regs auto-vmcnt'd
//   B1        -- all waves' A(kt) landed; also proves all waves' reads of
//                buf^1 (tile kt-1) are done (lgkm-before-MFMA-before-B1)
//   stageA(kt+1 -> buf^1)   [kt<7]
//   compute: 8 ds_read_b128 (A, buf) + B regs -> 16 mfma_scale
//   loadB(kt+1)             [kt<7]  (8 coalesced 1KB loads)
__global__ __launch_bounds__(256, 3) void gemm_min_mx(const unsigned char* __restrict__ e8,
                                                      const unsigned char* __restrict__ c8t,
                                                      const float* __restrict__ csq,
                                                      float* __restrict__ pmin) {
  __shared__ __align__(16) char lds[2 * ABUF];
  __shared__ float rowmin2[2][BM4];

  const int t = threadIdx.x;
  const int w = t >> 6;
  const int l = t & 63;
  const int wr = w >> 1, wc = w & 1;  // 2x2 wave grid, 64x64 tiles
  const int g = l >> 4, lr = l & 15;

  // XCD swizzle: XCD k owns swz in [1568k,1568k+1568) = rp in [98k,98k+98)
  // x all 16 ct. c8t (2 MB) L2-resident; A panel (128 KB) reused 16x L2-hot.
  const int b = blockIdx.x;
  const int swz = (b & 7) * BPX4 + (b >> 3);
  const int rp = swz >> 4, ct = swz & 15;
  const long row0 = (long)rp * BM4;
  const int col0 = ct * BN4;

  // A staging: dest linear d = i*4096 + t*16 -> row = i*32+(t>>3), slot = t&7
  // (row&7 i-invariant). source = row*1024 + kt*128 + ((slot^(row&7))<<4).
  const int trow = t >> 3, tsl = t & 7;
  const int ssw = (tsl ^ (trow & 7)) << 4;
  const unsigned char* srcA0 = e8 + (row0 + trow) * (size_t)D_K + ssw;
  const int dst0 = t * 16;

  // B direct pointers into c8t: frag (n, ksp) at
  //   ((kt*8 + ksp*4 + g)*2048 + col)*16, col = col0+wc*64+n*16+lr.
  const unsigned char* colp[4];
#pragma unroll
  for (int n = 0; n < 4; ++n)
    colp[n] = c8t + ((size_t)g * 2048 + (col0 + wc * 64 + n * 16 + lr)) * 16;

  f32x4 acc[4][4];
#pragma unroll
  for (int m = 0; m < 4; ++m)
#pragma unroll
    for (int n = 0; n < 4; ++n) acc[m][n] = (f32x4){0.f, 0.f, 0.f, 0.f};

  // A frag bases: row&7 == lr&7 independent of m/wr -> m-invariant swizzle.
  const int swsel = lr & 7;
  const char* aBase0 = lds + (wr * 64 + lr) * 128 + ((g ^ swsel) << 4);
  const char* aBase1 = lds + (wr * 64 + lr) * 128 + (((4 + g) ^ swsel) << 4);

  i32x4 bLo[4], bHi[4];

  auto stageA = [&](int kt, int buf) {
    const size_t ko = (size_t)kt * BK4;
    char* base = lds + buf * ABUF;
#pragma unroll
    for (int i = 0; i < 4; ++i)
      __builtin_amdgcn_global_load_lds(
          (const AS1 unsigned int*)(const void*)(srcA0 + (size_t)i * 32 * D_K + ko),
          (AS3 unsigned int*)(void*)(base + i * 4096 + dst0), 16, 0, 0);
  };

  auto loadB = [&](int kt) {
#pragma unroll
    for (int n = 0; n < 4; ++n) {
      bLo[n] = *reinterpret_cast<const i32x4*>(colp[n] + (size_t)kt * 262144);
      bHi[n] = *reinterpret_cast<const i32x4*>(colp[n] + (size_t)kt * 262144 + 131072);
    }
  };

  // A from LDS + preloaded B -> 16 mfma_scale (K=128, unit e8m0 scales)
  auto compute_tile = [&](int bo) {
    i32x8 b8[4];
#pragma unroll
    for (int n = 0; n < 4; ++n)
      b8[n] = __builtin_shufflevector(bLo[n], bHi[n], 0, 1, 2, 3, 4, 5, 6, 7);
#pragma unroll
    for (int m = 0; m < 4; ++m) {
      const i32x4 lo = *reinterpret_cast<const i32x4*>(aBase0 + bo + m * 2048);
      const i32x4 hi = *reinterpret_cast<const i32x4*>(aBase1 + bo + m * 2048);
      const i32x8 a8 = __builtin_shufflevector(lo, hi, 0, 1, 2, 3, 4, 5, 6, 7);
#pragma unroll
      for (int n = 0; n < 4; ++n)
        acc[m][n] = __builtin_amdgcn_mfma_scale_f32_16x16x128_f8f6f4(
            a8, b8[n], acc[m][n], 0 /*fp8 A*/, 0 /*fp8 B*/, 0, 0x7F7F7F7F, 0,
            0x7F7F7F7F);
    }
  };

  // prologue: A(0) staged (oldest in queue), then B(0)
  stageA(0, 0);
  FENCE;
  loadB(0);
#pragma unroll
  for (int kt = 0; kt < NT4; ++kt) {
    const int buf = kt & 1;
    WAITVM(8);  // retire 4 oldest = stageA(kt); B(kt) handled by compiler
    FENCE;
    __builtin_amdgcn_s_barrier();  // B1: A(kt) landed; buf^1 reads all done
    FENCE;
    if (kt < NT4 - 1) {
      stageA(kt + 1, buf ^ 1);  // safe: after B1, all reads of buf^1 done
      FENCE;                    // pin issue order: A-stage before B loads
    }
    compute_tile(buf * ABUF);
    if (kt < NT4 - 1) {
      FENCE;
      loadB(kt + 1);  // reuse B regs after last use in compute_tile
    }
  }

  // --- partial min over this block's 128 cols: val = ||c||^2 - 2*dot ---
  float runmin[4][4];
#pragma unroll
  for (int m = 0; m < 4; ++m)
#pragma unroll
    for (int r = 0; r < 4; ++r) runmin[m][r] = 3.0e38f;
#pragma unroll
  for (int n = 0; n < 4; ++n) {
    const float cs = csq[col0 + wc * 64 + n * 16 + lr];
#pragma unroll
    for (int m = 0; m < 4; ++m)
#pragma unroll
      for (int r = 0; r < 4; ++r)
        runmin[m][r] = fminf(runmin[m][r], cs - 2.0f * acc[m][n][r]);
  }
#pragma unroll
  for (int m = 0; m < 4; ++m)
#pragma unroll
    for (int r = 0; r < 4; ++r) {
      float v = runmin[m][r];
      v = fminf(v, __shfl_xor(v, 1));
      v = fminf(v, __shfl_xor(v, 2));
      v = fminf(v, __shfl_xor(v, 4));
      v = fminf(v, __shfl_xor(v, 8));
      runmin[m][r] = v;
    }
  if (lr == 0) {
#pragma unroll
    for (int m = 0; m < 4; ++m)
#pragma unroll
      for (int r = 0; r < 4; ++r)
        rowmin2[wc][wr * 64 + m * 16 + g * 4 + r] = runmin[m][r];
  }
  __syncthreads();
  if (t < BM4) {
    pmin[(row0 + t) * NCT4 + ct] = fminf(rowmin2[0][t], rowmin2[1][t]);
  }
}

// ---- final: 16-way min + sqrt ----
__global__ __launch_bounds__(256) void final_min(const float* __restrict__ esq,
                                                 const float* __restrict__ pmin,
                                                 float* __restrict__ out) {
  const int r = blockIdx.x * 256 + threadIdx.x;
  const float4* p = reinterpret_cast<const float4*>(pmin + (size_t)r * 16);
  float4 a = p[0], b = p[1], c = p[2], d = p[3];
  float m = fminf(fminf(fminf(a.x, a.y), fminf(a.z, a.w)),
                  fminf(fminf(b.x, b.y), fminf(b.z, b.w)));
  m = fminf(m, fminf(fminf(fminf(c.x, c.y), fminf(c.z, c.w)),
                     fminf(fminf(d.x, d.y), fminf(d.z, d.w))));
  out[r] = sqrtf(fmaxf(esq[r] + m, 0.f));
}

// ---- bf16 prep (fallback path) ----
__global__ __launch_bounds__(256) void rowsq_bf16(const float* __restrict__ src,
                                                  __bf16* __restrict__ dst,
                                                  float* __restrict__ sq) {
  const int m = blockIdx.x;
  const int t = threadIdx.x;
  const float4 v = *reinterpret_cast<const float4*>(src + (size_t)m * D_K + t * 4);
  bf16x4 o = {(__bf16)v.x, (__bf16)v.y, (__bf16)v.z, (__bf16)v.w};
  *reinterpret_cast<bf16x4*>(dst + (size_t)m * D_K + t * 4) = o;
  float ss = v.x * v.x + v.y * v.y + v.z * v.z + v.w * v.w;
  ss += __shfl_xor(ss, 1);
  ss += __shfl_xor(ss, 2);
  ss += __shfl_xor(ss, 4);
  ss += __shfl_xor(ss, 8);
  ss += __shfl_xor(ss, 16);
  ss += __shfl_xor(ss, 32);
  __shared__ float ws4[4];
  const int w = t >> 6, l = t & 63;
  if (l == 0) ws4[w] = ss;
  __syncthreads();
  if (t == 0) sq[m] = ws4[0] + ws4[1] + ws4[2] + ws4[3];
}

// =================== round-1 fallback (proven) ===================
template <bool WS>
__global__ __launch_bounds__(256, 2) void fused_min(const float* __restrict__ embeds,
                                                    const float* __restrict__ centf,
                                                    const __bf16* __restrict__ cbf,
                                                    const float* __restrict__ csq,
                                                    float* __restrict__ out) {
  __shared__ __align__(16) char Ab[TM * 128];
  __shared__ __align__(16) char Bb[TN * 128];
  __shared__ float rowmin2[2][TM];
  __shared__ float sqrow[TM];
  __shared__ float colsq[TN];

  const int t = threadIdx.x;
  const int w = t >> 6;
  const int l = t & 63;
  const int wr = w >> 1, wc = w & 1;
  const int g = l >> 4, lr = l & 15;
  const long row0 = (long)blockIdx.x * TM;

  float runmin[4][4];
#pragma unroll
  for (int m = 0; m < 4; ++m)
#pragma unroll
    for (int r = 0; r < 4; ++r) runmin[m][r] = 3.0e38f;

  float sqpart[8];
#pragma unroll
  for (int c = 0; c < 8; ++c) sqpart[c] = 0.f;

  for (int nt = 0; nt < NT_TILES; ++nt) {
    const int col0 = nt * TN;
    f32x4 acc[4][4];
#pragma unroll
    for (int m = 0; m < 4; ++m)
#pragma unroll
      for (int n = 0; n < 4; ++n) acc[m][n] = (f32x4){0.f, 0.f, 0.f, 0.f};

    float cpart[8];
    if constexpr (!WS) {
#pragma unroll
      for (int c = 0; c < 8; ++c) cpart[c] = 0.f;
    }

    for (int kt = 0; kt < KT_STEPS; ++kt) {
      __syncthreads();
      if constexpr (WS) {
#pragma unroll
        for (int i = 0; i < 4; ++i) {
          const int s = (w * 4 + i) * 64 + l;
          const int col = s >> 3, sl = s & 7;
          const __bf16* src =
              cbf + (size_t)(col0 + col) * D_K + kt * BK + ((sl ^ (col & 7)) << 3);
          __builtin_amdgcn_global_load_lds(
              (const AS1 unsigned int*)(const void*)src,
              (AS3 unsigned int*)(void*)(Bb + (w * 4 + i) * 1024), 16, 0, 0);
        }
      } else {
#pragma unroll
        for (int c = 0; c < 8; ++c) {
          const int f = c * 256 + t;
          const int col = f >> 4, kq = f & 15;
          const float4 v = *reinterpret_cast<const float4*>(
              centf + (size_t)(col0 + col) * D_K + kt * BK + kq * 4);
          cpart[c] += v.x * v.x + v.y * v.y + v.z * v.z + v.w * v.w;
          bf16x4 o = {(__bf16)v.x, (__bf16)v.y, (__bf16)v.z, (__bf16)v.w};
          const int slot = kq >> 1;
          *reinterpret_cast<bf16x4*>(Bb + col * 128 + ((slot ^ (col & 7)) << 4) +
                                     (kq & 1) * 8) = o;
        }
      }
#pragma unroll
      for (int c = 0; c < 8; ++c) {
        const int f = c * 256 + t;
        const int row = f >> 4, kq = f & 15;
        const float4 v = *reinterpret_cast<const float4*>(
            embeds + (row0 + row) * (long)D_K + kt * BK + kq * 4);
        if (nt == 0) sqpart[c] += v.x * v.x + v.y * v.y + v.z * v.z + v.w * v.w;
        bf16x4 o = {(__bf16)v.x, (__bf16)v.y, (__bf16)v.z, (__bf16)v.w};
        const int slot = kq >> 1;
        *reinterpret_cast<bf16x4*>(Ab + row * 128 + ((slot ^ (row & 7)) << 4) +
                                   (kq & 1) * 8) = o;
      }
      __syncthreads();
#pragma unroll
      for (int ks = 0; ks < 2; ++ks) {
        bf16x8 af[4], bfr[4];
#pragma unroll
        for (int m = 0; m < 4; ++m) {
          const int row = wr * 64 + m * 16 + lr;
          const int slot = ks * 4 + g;
          af[m] = *reinterpret_cast<const bf16x8*>(Ab + row * 128 +
                                                   ((slot ^ (row & 7)) << 4));
        }
#pragma unroll
        for (int n = 0; n < 4; ++n) {
          const int col = wc * 64 + n * 16 + lr;
          const int slot = ks * 4 + g;
          bfr[n] = *reinterpret_cast<const bf16x8*>(Bb + col * 128 +
                                                    ((slot ^ (col & 7)) << 4));
        }
#pragma unroll
        for (int m = 0; m < 4; ++m)
#pragma unroll
          for (int n = 0; n < 4; ++n)
            acc[m][n] =
                __builtin_amdgcn_mfma_f32_16x16x32_bf16(af[m], bfr[n], acc[m][n], 0, 0, 0);
      }
    }

    if (nt == 0) {
#pragma unroll
      for (int c = 0; c < 8; ++c) {
        float ss = sqpart[c];
        ss += __shfl_xor(ss, 1);
        ss += __shfl_xor(ss, 2);
        ss += __shfl_xor(ss, 4);
        ss += __shfl_xor(ss, 8);
        if (lr == 0) sqrow[c * 16 + (w * 4 + g)] = ss;
      }
    }
    if constexpr (!WS) {
#pragma unroll
      for (int c = 0; c < 8; ++c) {
        float ss = cpart[c];
        ss += __shfl_xor(ss, 1);
        ss += __shfl_xor(ss, 2);
        ss += __shfl_xor(ss, 4);
        ss += __shfl_xor(ss, 8);
        if (lr == 0) colsq[c * 16 + (w * 4 + g)] = ss;
      }
      __syncthreads();
    }

#pragma unroll
    for (int n = 0; n < 4; ++n) {
      float cs;
      if constexpr (WS)
        cs = csq[col0 + wc * 64 + n * 16 + lr];
      else
        cs = colsq[wc * 64 + n * 16 + lr];
#pragma unroll
      for (int m = 0; m < 4; ++m)
#pragma unroll
        for (int r = 0; r < 4; ++r)
          runmin[m][r] = fminf(runmin[m][r], cs - 2.0f * acc[m][n][r]);
    }
  }

#pragma unroll
  for (int m = 0; m < 4; ++m)
#pragma unroll
    for (int r = 0; r < 4; ++r) {
      float v = runmin[m][r];
      v = fminf(v, __shfl_xor(v, 1));
      v = fminf(v, __shfl_xor(v, 2));
      v = fminf(v, __shfl_xor(v, 4));
      v = fminf(v, __shfl_xor(v, 8));
      runmin[m][r] = v;
    }
  if (lr == 0) {
#pragma unroll
    for (int m = 0; m < 4; ++m)
#pragma unroll
      for (int r = 0; r < 4; ++r)
        rowmin2[wc][wr * 64 + m * 16 + g * 4 + r] = runmin[m][r];
  }
  __syncthreads();
  if (t < TM) {
    const float v = fminf(rowmin2[0][t], rowmin2[1][t]);
    out[row0 + t] = sqrtf(fmaxf(sqrow[t] + v, 0.f));
  }
}

extern "C" void kernel_launch(void* const* d_in, const int* in_sizes, int n_in,
                              void* d_out, int out_size, void* d_ws, size_t ws_size,
                              hipStream_t stream) {
  const float* embeds = (const float*)d_in[0];
  const float* cent = (const float*)d_in[1];
  float* out = (float*)d_out;

  // ws layout for the fp8 fast path (~112 MiB)
  const size_t off_c8 = 0;
  const size_t off_csq = off_c8 + (size_t)M_CENT * D_K;             // 2 MiB
  const size_t off_e8 = off_csq + (size_t)M_CENT * 4;               // +8 KiB
  const size_t off_esq = off_e8 + (size_t)N_ROWS * D_K;             // +98 MiB
  const size_t off_pmin = off_esq + (size_t)N_ROWS * 4;             // +392 KiB
  const size_t need_full = off_pmin + (size_t)N_ROWS * NCT4 * 4;    // +6.1 MiB
  const size_t need_small = (size_t)M_CENT * D_K * 2 + (size_t)M_CENT * 4;

  if (ws_size >= need_full) {
    unsigned char* c8t = (unsigned char*)d_ws + off_c8;
    float* csq = (float*)((char*)d_ws + off_csq);
    unsigned char* e8 = (unsigned char*)d_ws + off_e8;
    float* esq = (float*)((char*)d_ws + off_esq);
    float* pmin = (float*)((char*)d_ws + off_pmin);
    rowsq_fp8packT<<<M_CENT, 256, 0, stream>>>(cent, c8t, csq);
    rowsq_fp8pack<<<N_ROWS, 256, 0, stream>>>(embeds, e8, esq);
    gemm_min_mx<<<NBLK4, 256, 0, stream>>>(e8, c8t, csq, pmin);
    final_min<<<N_ROWS / 256, 256, 0, stream>>>(esq, pmin, out);
  } else if (ws_size >= need_small) {
    __bf16* cbf = (__bf16*)d_ws;
    float* csq = (float*)((char*)d_ws + (size_t)M_CENT * D_K * 2);
    rowsq_bf16<<<M_CENT, 256, 0, stream>>>(cent, cbf, csq);
    fused_min<true><<<N_ROWS / TM, 256, 0, stream>>>(embeds, cent, cbf, csq, out);
  } else {
    fused_min<false><<<N_ROWS / TM, 256, 0, stream>>>(embeds, cent, nullptr, nullptr, out);
  }
}